// Round 3
// baseline (156.978 us; speedup 1.0000x reference)
//
#include <hip/hip_runtime.h>

// Medical2DSliceRenderer on MI355X (gfx950) — round 3: packed-FP32 (v_pk_*_f32)
//
// Per pixel p, slice s, chunk c:
//   S1[c] = sum_g exp2(qa dx^2 + qb dx dy + qd dy^2 + log2(op*mask))  (= g*op)
//   S2[c] = sum_g (g*op)^2 * (ft/op)                                  (= g^2*op*ft)
//   img += (1-acc)*S2[c];  acc += (1-acc)*S1[c]
//
// Round-3 structure: each lane renders TWO pixels (cols j and j+64 of one
// row, same y) using <2 x float> ops -> VOP3P v_pk_{add,mul,fma}_f32.
// Every per-gaussian field is stored DUPLICATED as a 64-bit pair (and mu2d
// stored negated), so VOP3P reads it straight from an SGPR pair: the inner
// loop is 10 pk-VALU + 2 v_exp_f32 per 2 pixels with zero broadcast movs.
// Gaussian data stays wave-uniform -> scalar pipe (s_load), no LDS.

#define EPSV 1e-6f
#define NG   4096
#define PP   16384
#define NSL  4
#define SPLIT 8
#define GPW  128         // gaussians per split per chunk (1024/8)

typedef float v2f __attribute__((ext_vector_type(2)));

__global__ void prep_kernel(const float* __restrict__ means,
                            const float* __restrict__ scales,
                            const float* __restrict__ rots,
                            const float* __restrict__ ops,
                            const float* __restrict__ fts,
                            float4* __restrict__ gdata) {
    __shared__ float red[256];
    int tid = threadIdx.x;

    // block-redundant max over scales[:,2]
    float m = -1e30f;
    for (int i = tid; i < NG; i += 256) m = fmaxf(m, scales[i*3+2]);
    red[tid] = m;
    __syncthreads();
    for (int s = 128; s > 0; s >>= 1) {
        if (tid < s) red[tid] = fmaxf(red[tid], red[tid+s]);
        __syncthreads();
    }
    float maxd = 3.0f * red[0];

    int g = blockIdx.x * 256 + tid;
    if (g >= NG) return;

    float qw = rots[g*4+0], qx = rots[g*4+1], qy = rots[g*4+2], qz = rots[g*4+3];
    float inorm = rsqrtf(qw*qw + qx*qx + qy*qy + qz*qz);
    qw *= inorm; qx *= inorm; qy *= inorm; qz *= inorm;

    float s0 = scales[g*3+0], s1 = scales[g*3+1], s2 = scales[g*3+2];

    float r00 = 1.f - 2.f*(qy*qy + qz*qz), r01 = 2.f*(qx*qy - qw*qz), r02 = 2.f*(qx*qz + qw*qy);
    float r10 = 2.f*(qx*qy + qw*qz), r11 = 1.f - 2.f*(qx*qx + qz*qz), r12 = 2.f*(qy*qz - qw*qx);
    float r20 = 2.f*(qx*qz - qw*qy), r21 = 2.f*(qy*qz + qw*qx), r22 = 1.f - 2.f*(qx*qx + qy*qy);

    float a00 = r00*s0, a01 = r01*s1, a02 = r02*s2;
    float a10 = r10*s0, a11 = r11*s1, a12 = r12*s2;
    float a20 = r20*s0, a21 = r21*s1, a22 = r22*s2;

    float c00 = a00*a00 + a01*a01 + a02*a02;
    float c01 = a00*a10 + a01*a11 + a02*a12;
    float c02 = a00*a20 + a01*a21 + a02*a22;
    float c11 = a10*a10 + a11*a11 + a12*a12;
    float c12 = a10*a20 + a11*a21 + a12*a22;
    float c22 = a20*a20 + a21*a21 + a22*a22;

    float izz = 1.0f / (c22 + EPSV);
    float kx = c02 * izz, ky = c12 * izz;
    float sa = c00 - c02*c02*izz + EPSV;
    float sb = c01 - c02*c12*izz;
    float sd = c11 - c12*c12*izz + EPSV;
    float det = sa*sd - sb*sb;
    float idet = 1.0f / det;

    const float C0 = -0.72134752044448170f;   // -0.5 * log2(e)
    float qa = C0 * sd * idet;
    float qb = C0 * (-2.0f * sb * idet);
    float qd = C0 * sa * idet;

    float mx = means[g*3+0], my = means[g*3+1], mz = means[g*3+2];
    float op = ops[g], ft = fts[g];

    #pragma unroll
    for (int s = 0; s < NSL; ++s) {
        float z = -0.15f + 0.1f * (float)s;
        float zoff = z - mz;
        float m2x = mx + kx * zoff;
        float m2y = my + ky * zoff;
        bool live = (fabsf(mz - z) < maxd) && (op > 1e-12f);
        float lop  = live ? __log2f(op) : -__builtin_inff();
        float ftop = live ? ft / op     : 0.f;
        float4* o = gdata + ((size_t)(s*NG + g)) * 4;
        o[0] = make_float4(-m2x, -m2x, -m2y, -m2y);
        o[1] = make_float4( qa,   qa,   qb,   qb );
        o[2] = make_float4( qd,   qd,   lop,  lop);
        o[3] = make_float4( ftop, ftop, 0.f,  0.f);
    }
}

__global__ __launch_bounds__(512)
void render_kernel(const v2f* __restrict__ gdata, float* __restrict__ out) {
    __shared__ float parts[SPLIT][64][20];   // stride 20 floats: 16B-aligned rows

    int tid   = threadIdx.x;
    int lane  = tid & 63;
    int split = __builtin_amdgcn_readfirstlane(tid >> 6);   // 0..7, wave-uniform
    int slice = blockIdx.x >> 7;
    int row   = blockIdx.x & 127;

    const float DL = 2.0f / 127.0f;
    float xlo = -1.0f + (float)lane * DL;
    float y   = -1.0f + (float)row  * DL;
    v2f xP; xP.x = xlo; xP.y = xlo + 64.0f * DL;   // cols lane, lane+64
    v2f yP; yP.x = y;   yP.y = y;

    const v2f* gs = gdata + (size_t)slice * NG * 8;   // 8 v2f per gaussian

    #pragma unroll
    for (int c = 0; c < 4; ++c) {
        const v2f* p = gs + (size_t)(c * 1024 + split * GPW) * 8;  // uniform addr
        v2f a1 = {0.f, 0.f}, a2 = {0.f, 0.f};
        #pragma unroll 4
        for (int g = 0; g < GPW; ++g) {
            const v2f* q = p + g * 8;
            v2f nmx = q[0], nmy = q[1], qa = q[2], qb = q[3];
            v2f qd  = q[4], lop = q[5], ftp = q[6];
            v2f dx = xP + nmx;                               // pk_add (stored -mu)
            v2f dy = yP + nmy;                               // pk_add
            v2f e  = __builtin_elementwise_fma(qd * dy, dy, lop);   // pk_mul+pk_fma
            v2f t  = __builtin_elementwise_fma(qa, dx, qb * dy);    // pk_mul+pk_fma
            v2f mm = __builtin_elementwise_fma(dx, t, e);           // pk_fma
            v2f gv;
            gv.x = __builtin_amdgcn_exp2f(mm.x);
            gv.y = __builtin_amdgcn_exp2f(mm.y);
            a1 += gv;                                        // pk_add
            a2 = __builtin_elementwise_fma(gv * gv, ftp, a2);       // pk_mul+pk_fma
        }
        parts[split][lane][c*4+0] = a1.x;
        parts[split][lane][c*4+1] = a1.y;
        parts[split][lane][c*4+2] = a2.x;
        parts[split][lane][c*4+3] = a2.y;
    }
    __syncthreads();

    if (tid < 64) {
        float imgl = 0.f, accl = 0.f, imgh = 0.f, acch = 0.f;
        #pragma unroll
        for (int c = 0; c < 4; ++c) {
            float S1l = 0.f, S1h = 0.f, S2l = 0.f, S2h = 0.f;
            #pragma unroll
            for (int s = 0; s < SPLIT; ++s) {
                S1l += parts[s][tid][c*4+0];
                S1h += parts[s][tid][c*4+1];
                S2l += parts[s][tid][c*4+2];
                S2h += parts[s][tid][c*4+3];
            }
            float oml = 1.f - accl, omh = 1.f - acch;
            imgl = fmaf(oml, S2l, imgl);  accl = fmaf(oml, S1l, accl);
            imgh = fmaf(omh, S2h, imgh);  acch = fmaf(omh, S1h, acch);
        }
        int base = slice * PP + row * 128;
        out[base + tid]      = imgl;
        out[base + tid + 64] = imgh;
    }
}

extern "C" void kernel_launch(void* const* d_in, const int* in_sizes, int n_in,
                              void* d_out, int out_size, void* d_ws, size_t ws_size,
                              hipStream_t stream) {
    const float* means  = (const float*)d_in[0];
    const float* scales = (const float*)d_in[1];
    const float* rots   = (const float*)d_in[2];
    const float* ops    = (const float*)d_in[3];
    const float* fts    = (const float*)d_in[4];
    float* out = (float*)d_out;

    float4* gdata = (float4*)d_ws;   // 4 slices * 4096 gaussians * 64B = 1 MB

    prep_kernel<<<NG/256, 256, 0, stream>>>(means, scales, rots, ops, fts, gdata);
    render_kernel<<<NSL*128, 512, 0, stream>>>((const v2f*)gdata, out);
}

// Round 4
// 130.305 us; speedup vs baseline: 1.2047x; 1.2047x over previous
//
#include <hip/hip_runtime.h>

// Medical2DSliceRenderer on MI355X (gfx950) — round 4
//
//   S1[c] = sum_g exp2(qa dx^2 + qb dx dy + qd dy^2 + log2(op*mask))  (= g*op)
//   S2[c] = sum_g (g*op)^2 * (ft/op)                                  (= g^2*op*ft)
//   img += (1-acc)*S2[c];  acc += (1-acc)*S1[c]
//
// Round 4: packed FP32 (2 px/lane, VOP3P) kept from round 3; fixed the feed:
//  - table back to 32 B/gaussian; v2f splat {s,s} -> VOP3P op_sel broadcast
//    from ONE SGPR (<=1 SGPR per pk-op), halving scalar-load bytes
//  - SPLIT 16, 1024-thread blocks -> 32 waves/CU (8/SIMD) to hide s_load
//    latency (scalar loads drain lgkmcnt(0) -> only 1-group-deep pipelining)
//  - unroll 8: one prefetch group ~ covers one L2-hit latency

#define EPSV 1e-6f
#define NG   4096
#define PP   16384
#define NSL  4
#define SPLIT 16
#define GPC  64          // gaussians per split per chunk (1024/16)

typedef float v2f __attribute__((ext_vector_type(2)));

static __device__ __forceinline__ v2f splat(float s) { v2f r; r.x = s; r.y = s; return r; }

__global__ void prep_kernel(const float* __restrict__ means,
                            const float* __restrict__ scales,
                            const float* __restrict__ rots,
                            const float* __restrict__ ops,
                            const float* __restrict__ fts,
                            float4* __restrict__ gdata) {
    __shared__ float red[256];
    int tid = threadIdx.x;

    float m = -1e30f;
    for (int i = tid; i < NG; i += 256) m = fmaxf(m, scales[i*3+2]);
    red[tid] = m;
    __syncthreads();
    for (int s = 128; s > 0; s >>= 1) {
        if (tid < s) red[tid] = fmaxf(red[tid], red[tid+s]);
        __syncthreads();
    }
    float maxd = 3.0f * red[0];

    int g = blockIdx.x * 256 + tid;
    if (g >= NG) return;

    float qw = rots[g*4+0], qx = rots[g*4+1], qy = rots[g*4+2], qz = rots[g*4+3];
    float inorm = rsqrtf(qw*qw + qx*qx + qy*qy + qz*qz);
    qw *= inorm; qx *= inorm; qy *= inorm; qz *= inorm;

    float s0 = scales[g*3+0], s1 = scales[g*3+1], s2 = scales[g*3+2];

    float r00 = 1.f - 2.f*(qy*qy + qz*qz), r01 = 2.f*(qx*qy - qw*qz), r02 = 2.f*(qx*qz + qw*qy);
    float r10 = 2.f*(qx*qy + qw*qz), r11 = 1.f - 2.f*(qx*qx + qz*qz), r12 = 2.f*(qy*qz - qw*qx);
    float r20 = 2.f*(qx*qz - qw*qy), r21 = 2.f*(qy*qz + qw*qx), r22 = 1.f - 2.f*(qx*qx + qy*qy);

    float a00 = r00*s0, a01 = r01*s1, a02 = r02*s2;
    float a10 = r10*s0, a11 = r11*s1, a12 = r12*s2;
    float a20 = r20*s0, a21 = r21*s1, a22 = r22*s2;

    float c00 = a00*a00 + a01*a01 + a02*a02;
    float c01 = a00*a10 + a01*a11 + a02*a12;
    float c02 = a00*a20 + a01*a21 + a02*a22;
    float c11 = a10*a10 + a11*a11 + a12*a12;
    float c12 = a10*a20 + a11*a21 + a12*a22;
    float c22 = a20*a20 + a21*a21 + a22*a22;

    float izz = 1.0f / (c22 + EPSV);
    float kx = c02 * izz, ky = c12 * izz;
    float sa = c00 - c02*c02*izz + EPSV;
    float sb = c01 - c02*c12*izz;
    float sd = c11 - c12*c12*izz + EPSV;
    float det = sa*sd - sb*sb;
    float idet = 1.0f / det;

    const float C0 = -0.72134752044448170f;   // -0.5 * log2(e)
    float qa = C0 * sd * idet;
    float qb = C0 * (-2.0f * sb * idet);
    float qd = C0 * sa * idet;

    float mx = means[g*3+0], my = means[g*3+1], mz = means[g*3+2];
    float op = ops[g], ft = fts[g];

    #pragma unroll
    for (int s = 0; s < NSL; ++s) {
        float z = -0.15f + 0.1f * (float)s;
        float zoff = z - mz;
        float m2x = mx + kx * zoff;
        float m2y = my + ky * zoff;
        bool live = (fabsf(mz - z) < maxd) && (op > 1e-12f);
        float lop  = live ? __log2f(op) : -__builtin_inff();
        float ftop = live ? ft / op     : 0.f;
        float4* o = gdata + ((size_t)(s*NG + g)) * 2;
        o[0] = make_float4(-m2x, -m2y, qa, qb);
        o[1] = make_float4( qd,   lop,  ftop, 0.f);
    }
}

__global__ __launch_bounds__(1024)
void render_kernel(const float4* __restrict__ gdata, float* __restrict__ out) {
    __shared__ float parts[SPLIT][64][17];   // 69,632 B
    __shared__ float cres[4][64][5];         //  5,120 B

    int tid   = threadIdx.x;
    int lane  = tid & 63;
    int split = __builtin_amdgcn_readfirstlane(tid >> 6);   // 0..15, wave-uniform
    int slice = blockIdx.x >> 7;
    int row   = blockIdx.x & 127;

    const float DL = 2.0f / 127.0f;
    float xlo = -1.0f + (float)lane * DL;
    float y   = -1.0f + (float)row  * DL;
    v2f xP; xP.x = xlo; xP.y = xlo + 64.0f * DL;   // cols lane, lane+64
    v2f yP = splat(y);

    const float4* gs = gdata + (size_t)slice * NG * 2;

    #pragma unroll
    for (int c = 0; c < 4; ++c) {
        const float4* p = gs + (size_t)(c * 1024 + split * GPC) * 2;  // uniform
        v2f a1 = {0.f, 0.f}, a2 = {0.f, 0.f};
        #pragma unroll 8
        for (int g = 0; g < GPC; ++g) {
            float4 A = p[2*g+0];           // -m2x, -m2y, qa, qb   (s_load)
            float4 B = p[2*g+1];           // qd, lop, ftop, pad
            v2f dx = xP + splat(A.x);                                   // pk_add
            v2f dy = yP + splat(A.y);                                   // pk_add
            v2f e  = __builtin_elementwise_fma(splat(B.x) * dy, dy, splat(B.y));
            v2f t  = __builtin_elementwise_fma(splat(A.z), dx, splat(A.w) * dy);
            v2f mm = __builtin_elementwise_fma(dx, t, e);               // pk_fma
            v2f gv;
            gv.x = __builtin_amdgcn_exp2f(mm.x);
            gv.y = __builtin_amdgcn_exp2f(mm.y);
            a1 += gv;                                                   // pk_add
            a2 = __builtin_elementwise_fma(gv * gv, splat(B.z), a2);    // pk_fma
        }
        parts[split][lane][c*4+0] = a1.x;
        parts[split][lane][c*4+1] = a1.y;
        parts[split][lane][c*4+2] = a2.x;
        parts[split][lane][c*4+3] = a2.y;
    }
    __syncthreads();

    // stage 1: waves 0..3 fold the 16 splits for chunk = wave id
    if (split < 4) {
        float S1l = 0.f, S1h = 0.f, S2l = 0.f, S2h = 0.f;
        #pragma unroll
        for (int s = 0; s < SPLIT; ++s) {
            S1l += parts[s][lane][split*4+0];
            S1h += parts[s][lane][split*4+1];
            S2l += parts[s][lane][split*4+2];
            S2h += parts[s][lane][split*4+3];
        }
        cres[split][lane][0] = S1l;
        cres[split][lane][1] = S1h;
        cres[split][lane][2] = S2l;
        cres[split][lane][3] = S2h;
    }
    __syncthreads();

    // stage 2: wave 0 runs the sequential 4-chunk recursion
    if (split == 0) {
        float imgl = 0.f, accl = 0.f, imgh = 0.f, acch = 0.f;
        #pragma unroll
        for (int c = 0; c < 4; ++c) {
            float S1l = cres[c][lane][0], S1h = cres[c][lane][1];
            float S2l = cres[c][lane][2], S2h = cres[c][lane][3];
            float oml = 1.f - accl, omh = 1.f - acch;
            imgl = fmaf(oml, S2l, imgl);  accl = fmaf(oml, S1l, accl);
            imgh = fmaf(omh, S2h, imgh);  acch = fmaf(omh, S1h, acch);
        }
        int base = slice * PP + row * 128;
        out[base + lane]      = imgl;
        out[base + lane + 64] = imgh;
    }
}

extern "C" void kernel_launch(void* const* d_in, const int* in_sizes, int n_in,
                              void* d_out, int out_size, void* d_ws, size_t ws_size,
                              hipStream_t stream) {
    const float* means  = (const float*)d_in[0];
    const float* scales = (const float*)d_in[1];
    const float* rots   = (const float*)d_in[2];
    const float* ops    = (const float*)d_in[3];
    const float* fts    = (const float*)d_in[4];
    float* out = (float*)d_out;

    float4* gdata = (float4*)d_ws;   // 4*4096*32B = 512 KB

    prep_kernel<<<NG/256, 256, 0, stream>>>(means, scales, rots, ops, fts, gdata);
    render_kernel<<<NSL*128, 1024, 0, stream>>>(gdata, out);
}